// Round 9
// baseline (13854.868 us; speedup 1.0000x reference)
//
#include <hip/hip_runtime.h>

// LSTM T=4096, IN=32, H=512, OUT=32, 3 layers + projection.
// R9 = R7 with ONLY the dot partition changed: 2 rows x 32 k per lane
//   (was 1 row x 64 k). Halves LDS broadcast traffic (256->128 b128
//   wave-instrs/step/WG) while keeping R7's proven 64-float weight budget,
//   staging, tail, and publish byte-identical.
//   R8 post-mortem: 4 rows x 16 k needed 80 pinned floats -> allocator
//   pushed past the repeatedly-measured 64-float ceiling; VALUBusy collapsed
//   to 3.8% (stalls). R9 stays at 64.
// Layout: 32 WGs/layer x 1024 thr. wv=tid>>6, sg=lane>>5, cl=lane&31.
//   chunk = wv*2+sg. Layers 1/2: 32 chunks x 32 k over concat
//   [prev-h(512); own-h(512)]; chunk<16 -> Wih, else Whh. Lane's rows:
//   cl and cl+32 (same column, gates {i,f} / {g,o}). Layer 0: 32 chunks
//   x 16 k of own-h + 1 x-k per chunk.
//   Reduce: shfl_xor(32) per acc -> lanes<32 write float2 part[wv][cl][2];
//   wave0 tail and ONE coalesced 128B publish exactly as R7.
// Invariants (hard-won): no cache-wide fences (R2); no runtime indexing of
//   private arrays (R4); <=64 weight floats/lane (R5/R6/R8); publish = one
//   wave, one full line (R6).

#define T_SEQ 4096
#define HDIM  512
#define NWG_L 32
#define NTH   1024

typedef unsigned long long u64;

__device__ __forceinline__ u64 cohLoad(const u64* p) {
    return __hip_atomic_load(p, __ATOMIC_RELAXED, __HIP_MEMORY_SCOPE_AGENT);
}
__device__ __forceinline__ void cohStore(u64* p, u64 v) {
    __hip_atomic_store(p, v, __ATOMIC_RELAXED, __HIP_MEMORY_SCOPE_AGENT);
}
__device__ __forceinline__ float fsigmoid(float x) {
    return __builtin_amdgcn_rcpf(1.f + __expf(-x));
}
__device__ __forceinline__ float ftanh(float x) {
    float e = __expf(2.f * fabsf(x));           // +inf ok -> t = 1
    float t = 1.f - 2.f * __builtin_amdgcn_rcpf(e + 1.f);
    return copysignf(t, x);
}

// ---------------------------------------------------------------------------
// Tiled fp32 GEMM (final projection): C[M][N] = A[M][K] * B[N][K]^T + bias[n]
// ---------------------------------------------------------------------------
template <int BM, int BN, int BK>
__global__ __launch_bounds__(256)
void gemm_abt(const float* __restrict__ A, const float* __restrict__ B,
              const float* __restrict__ bias1,
              float* __restrict__ C, int M, int N, int K) {
    constexpr int NTX = BN / 4;
    constexpr int NTY = 256 / NTX;
    constexpr int TM  = BM / NTY;
    __shared__ float As[BM][BK + 1];
    __shared__ float Bs[BN][BK + 1];

    const int tid = threadIdx.x;
    const int tx = tid % NTX;
    const int ty = tid / NTX;
    const int m0 = blockIdx.y * BM;
    const int n0 = blockIdx.x * BN;

    float acc[TM][4];
    #pragma unroll
    for (int i = 0; i < TM; ++i)
        #pragma unroll
        for (int j = 0; j < 4; ++j) acc[i][j] = 0.f;

    for (int k0 = 0; k0 < K; k0 += BK) {
        constexpr int AV = BM * BK / 4;
        #pragma unroll
        for (int i = tid; i < AV; i += 256) {
            int r = i / (BK / 4), c4 = i % (BK / 4);
            float4 v = *(const float4*)(A + (size_t)(m0 + r) * K + k0 + c4 * 4);
            As[r][c4 * 4 + 0] = v.x; As[r][c4 * 4 + 1] = v.y;
            As[r][c4 * 4 + 2] = v.z; As[r][c4 * 4 + 3] = v.w;
        }
        constexpr int BV = BN * BK / 4;
        #pragma unroll
        for (int i = tid; i < BV; i += 256) {
            int r = i / (BK / 4), c4 = i % (BK / 4);
            float4 v = *(const float4*)(B + (size_t)(n0 + r) * K + k0 + c4 * 4);
            Bs[r][c4 * 4 + 0] = v.x; Bs[r][c4 * 4 + 1] = v.y;
            Bs[r][c4 * 4 + 2] = v.z; Bs[r][c4 * 4 + 3] = v.w;
        }
        __syncthreads();
        #pragma unroll
        for (int kk = 0; kk < BK; ++kk) {
            float a[TM], b[4];
            #pragma unroll
            for (int i = 0; i < TM; ++i) a[i] = As[ty * TM + i][kk];
            #pragma unroll
            for (int j = 0; j < 4; ++j) b[j] = Bs[tx * 4 + j][kk];
            #pragma unroll
            for (int i = 0; i < TM; ++i)
                #pragma unroll
                for (int j = 0; j < 4; ++j) acc[i][j] += a[i] * b[j];
        }
        __syncthreads();
    }

    #pragma unroll
    for (int j = 0; j < 4; ++j) {
        float bv = bias1 ? bias1[n0 + tx * 4 + j] : 0.f;
        #pragma unroll
        for (int i = 0; i < TM; ++i) acc[i][j] += bv;
    }
    #pragma unroll
    for (int i = 0; i < TM; ++i) {
        int m = m0 + ty * TM + i;
        float4 v = make_float4(acc[i][0], acc[i][1], acc[i][2], acc[i][3]);
        *(float4*)(C + (size_t)m * N + n0 + tx * 4) = v;
    }
}

// ---------------------------------------------------------------------------
__global__ void unpack_h(const u64* __restrict__ hp, float* __restrict__ out,
                         int n) {
    int i = blockIdx.x * blockDim.x + threadIdx.x;
    if (i < n) out[i] = __uint_as_float((unsigned)hp[i]);
}

// ---------------------------------------------------------------------------
__global__ __launch_bounds__(NTH, 4)
void lstm_fused(const float* __restrict__ seq,
                const float* __restrict__ Wih1, const float* __restrict__ Whh1,
                const float* __restrict__ bih1, const float* __restrict__ bhh1,
                const float* __restrict__ Wih2, const float* __restrict__ Whh2,
                const float* __restrict__ bih2, const float* __restrict__ bhh2,
                const float* __restrict__ Wih3, const float* __restrict__ Whh3,
                const float* __restrict__ bih3, const float* __restrict__ bhh3,
                u64* __restrict__ hp) {
    // layers 1/2: h_in = [prev-h(512) | own-h(512)]
    // layer 0:    h_in = [own-h(512) | x(32)]
    __shared__ __align__(16) float h_in[2][1024 + 32];
    __shared__ __align__(16) float part[16 * 64];   // [wv][cl][2] as float2

    const int blk   = blockIdx.x;
    const int layer = blk >> 5;
    const int g     = blk & 31;
    const int tid   = threadIdx.x;
    const int wv    = tid >> 6;          // 0..15
    const int lane  = tid & 63;
    const int sg    = lane >> 5;         // sub-group 0/1
    const int cl    = lane & 31;         // row base within WG (row cl, cl+32)
    const int chunk = wv * 2 + sg;       // k-chunk 0..31

    const float* Wih = layer == 0 ? Wih1 : (layer == 1 ? Wih2 : Wih3);
    const float* Whh = layer == 0 ? Whh1 : (layer == 1 ? Whh2 : Whh3);
    const float* bih = layer == 0 ? bih1 : (layer == 1 ? bih2 : bih3);
    const float* bhh = layer == 0 ? bhh1 : (layer == 1 ? bhh2 : bhh3);

    // This lane's two rows: r0 = cl (gates i/f), r1 = cl+32 (gates g/o),
    // same column g*16 + (cl&15).
    const int grow0 = (cl >> 4) * HDIM + g * 16 + (cl & 15);
    const int grow1 = (2 + (cl >> 4)) * HDIM + g * 16 + (cl & 15);

    // ---- 64 weight floats/lane into registers (loop-constant indexing) ----
    // layers 1/2: w[0..31] = row r0, k [chunk*32, +32); w[32..63] = row r1.
    // layer 0:    w[0..15] = row r0 h-k [chunk*16,+16); w[16..31] = row r1;
    //             w[32] = Wih[r0][chunk]; w[33] = Wih[r1][chunk].
    float w[64];
    #pragma unroll
    for (int m = 0; m < 64; ++m) w[m] = 0.f;
    if (layer == 0) {
        const int k0 = chunk * 16;
        const float* wp0 = Whh + (size_t)grow0 * HDIM + k0;
        const float* wp1 = Whh + (size_t)grow1 * HDIM + k0;
        #pragma unroll
        for (int k4 = 0; k4 < 4; ++k4) {
            float4 v0 = ((const float4*)wp0)[k4];
            w[4*k4+0]=v0.x; w[4*k4+1]=v0.y; w[4*k4+2]=v0.z; w[4*k4+3]=v0.w;
            float4 v1 = ((const float4*)wp1)[k4];
            w[16+4*k4+0]=v1.x; w[16+4*k4+1]=v1.y;
            w[16+4*k4+2]=v1.z; w[16+4*k4+3]=v1.w;
        }
        w[32] = Wih[(size_t)grow0 * 32 + chunk];
        w[33] = Wih[(size_t)grow1 * 32 + chunk];
    } else {
        const float* Wsrc = (chunk < 16) ? Wih : Whh;
        const int k0 = (chunk & 15) * 32;
        const float* wp0 = Wsrc + (size_t)grow0 * HDIM + k0;
        const float* wp1 = Wsrc + (size_t)grow1 * HDIM + k0;
        #pragma unroll
        for (int k4 = 0; k4 < 8; ++k4) {
            float4 v0 = ((const float4*)wp0)[k4];
            w[4*k4+0]=v0.x; w[4*k4+1]=v0.y; w[4*k4+2]=v0.z; w[4*k4+3]=v0.w;
            float4 v1 = ((const float4*)wp1)[k4];
            w[32+4*k4+0]=v1.x; w[32+4*k4+1]=v1.y;
            w[32+4*k4+2]=v1.z; w[32+4*k4+3]=v1.w;
        }
    }
    #pragma unroll
    for (int m = 0; m < 64; ++m) asm volatile("" : "+v"(w[m]));

    // bias for wave-0 tail (lane = gate*16+c owns row gate*512+g*16+c)
    const float brow = bih[(lane >> 4) * HDIM + g * 16 + (lane & 15)]
                     + bhh[(lane >> 4) * HDIM + g * 16 + (lane & 15)];

    u64*       hpOwn  = hp + (size_t)layer * T_SEQ * HDIM;
    const u64* hpPrev = hp + (size_t)(layer > 0 ? layer - 1 : 0) * T_SEQ * HDIM;

    float c = 0.f;   // cell state (wave 0, lanes 0..15)

    for (unsigned t = 0; t < T_SEQ; ++t) {
        const int pb = t & 1;
        // ---- stage: each thread polls exactly one element (tag = data) ----
        if (layer == 0) {
            if (tid < HDIM) {
                float hv = 0.f;
                if (t > 0) {
                    const u64* ph = hpOwn + (size_t)(t - 1) * HDIM + tid;
                    u64 v;
                    do { v = cohLoad(ph); } while ((unsigned)(v >> 32) != t);
                    hv = __uint_as_float((unsigned)v);
                }
                h_in[pb][tid] = hv;
            } else if (tid < HDIM + 32) {
                h_in[pb][tid] = seq[(size_t)t * 32 + (tid - HDIM)];
            }
        } else {
            if (tid < HDIM) {                    // prev-layer h[t], tag t+1
                const u64* px = hpPrev + (size_t)t * HDIM + tid;
                u64 v;
                do { v = cohLoad(px); } while ((unsigned)(v >> 32) != t + 1u);
                h_in[pb][tid] = __uint_as_float((unsigned)v);
            } else {                             // own h[t-1], tag t
                float hv = 0.f;
                if (t > 0) {
                    const u64* ph = hpOwn + (size_t)(t - 1) * HDIM + (tid - HDIM);
                    u64 v;
                    do { v = cohLoad(ph); } while ((unsigned)(v >> 32) != t);
                    hv = __uint_as_float((unsigned)v);
                }
                h_in[pb][tid] = hv;
            }
        }
        __syncthreads();

        // ---- dot: 2 rows x 32 k (or 16 h-k + 1 x-k) per lane ----
        float p0 = 0.f, p1 = 0.f;
        if (layer == 0) {
            const float4* hb = (const float4*)(h_in[pb]) + chunk * 4;
            #pragma unroll
            for (int k4 = 0; k4 < 4; ++k4) {
                float4 hv = hb[k4];
                p0 += w[4*k4+0]*hv.x + w[4*k4+1]*hv.y
                    + w[4*k4+2]*hv.z + w[4*k4+3]*hv.w;
                p1 += w[16+4*k4+0]*hv.x + w[16+4*k4+1]*hv.y
                    + w[16+4*k4+2]*hv.z + w[16+4*k4+3]*hv.w;
            }
            float xval = h_in[pb][HDIM + chunk];
            p0 += w[32] * xval;
            p1 += w[33] * xval;
        } else {
            const float4* hb = (const float4*)(h_in[pb]) + chunk * 8;
            #pragma unroll
            for (int k4 = 0; k4 < 8; ++k4) {
                float4 hv = hb[k4];
                p0 += w[4*k4+0]*hv.x + w[4*k4+1]*hv.y
                    + w[4*k4+2]*hv.z + w[4*k4+3]*hv.w;
                p1 += w[32+4*k4+0]*hv.x + w[32+4*k4+1]*hv.y
                    + w[32+4*k4+2]*hv.z + w[32+4*k4+3]*hv.w;
            }
        }

        // ---- combine the 2 sub-groups; lanes<32 write float2 partials ----
        p0 += __shfl_xor(p0, 32, 64);
        p1 += __shfl_xor(p1, 32, 64);
        if (lane < 32)
            ((float2*)part)[wv * 32 + lane] = make_float2(p0, p1);
        __syncthreads();

        // ---- wave 0: cross-wave sum, gates, ONE coalesced 128B publish ----
        if (wv == 0) {
            // row r = lane; partial at part[wvv][lane&31][lane>>5]
            float tot = brow;
            #pragma unroll
            for (int wvv = 0; wvv < 16; ++wvv)
                tot += part[wvv * 64 + (lane & 31) * 2 + (lane >> 5)];
            const int c16 = lane & 15;
            float ai = __shfl(tot, c16 +  0, 64);
            float af = __shfl(tot, c16 + 16, 64);
            float ag = __shfl(tot, c16 + 32, 64);
            float ao = __shfl(tot, c16 + 48, 64);
            if (lane < 16) {
                float iv = fsigmoid(ai);
                float fv = fsigmoid(af);
                float gv = ftanh(ag);
                float ov = fsigmoid(ao);
                c = fv * c + iv * gv;
                float h = ov * ftanh(c);
                u64 pkt = (u64)__float_as_uint(h) | ((u64)(t + 1u) << 32);
                cohStore(hpOwn + (size_t)t * HDIM + g * 16 + lane, pkt);
            }
        }
        // next staging writes the other h_in buffer; part(t+1) writes happen
        // only after the post-staging barrier of t+1, which wave 0 joins
        // after its tail reads of part(t) -> safe.
    }
}

// ---------------------------------------------------------------------------
extern "C" void kernel_launch(void* const* d_in, const int* in_sizes, int n_in,
                              void* d_out, int out_size, void* d_ws, size_t ws_size,
                              hipStream_t stream) {
    const float* seq   = (const float*)d_in[0];
    const float* W_ih1 = (const float*)d_in[1];
    const float* W_hh1 = (const float*)d_in[2];
    const float* b_ih1 = (const float*)d_in[3];
    const float* b_hh1 = (const float*)d_in[4];
    const float* W_ih2 = (const float*)d_in[5];
    const float* W_hh2 = (const float*)d_in[6];
    const float* b_ih2 = (const float*)d_in[7];
    const float* b_hh2 = (const float*)d_in[8];
    const float* W_ih3 = (const float*)d_in[9];
    const float* W_hh3 = (const float*)d_in[10];
    const float* b_ih3 = (const float*)d_in[11];
    const float* b_hh3 = (const float*)d_in[12];
    const float* W_out = (const float*)d_in[13];
    const float* b_out = (const float*)d_in[14];
    float* out = (float*)d_out;

    // Workspace: hp[3][T][512] packed u64 (50.3MB); hs2 floats reuse the
    // dead layer-0 packed region after the recurrence.
    u64*   hp   = (u64*)d_ws;
    float* hs2f = (float*)d_ws;
    const u64* hp2 = hp + (size_t)2 * T_SEQ * HDIM;

    hipMemsetAsync(hp, 0, (size_t)3 * T_SEQ * HDIM * sizeof(u64), stream);

    lstm_fused<<<3 * NWG_L, NTH, 0, stream>>>(
        seq, W_ih1, W_hh1, b_ih1, b_hh1, W_ih2, W_hh2, b_ih2, b_hh2,
        W_ih3, W_hh3, b_ih3, b_hh3, hp);

    const int n = T_SEQ * HDIM;
    unpack_h<<<(n + 255) / 256, 256, 0, stream>>>(hp2, hs2f, n);

    gemm_abt<64, 32, 32><<<dim3(1, T_SEQ / 64), 256, 0, stream>>>(
        hs2f, W_out, b_out, out, T_SEQ, 32, HDIM);
}

// Round 10
// 6359.675 us; speedup vs baseline: 2.1785x; 2.1785x over previous
//
#include <hip/hip_runtime.h>

// LSTM T=4096, IN=32, H=512, OUT=32, 3 layers + projection.
// R10: register-broadcast GEMV ("readlane dot") on the R7 sync protocol.
//   R8/R9 falsified the LDS-volume model: wave-uniform broadcast b128 reads
//   are the CHEAP case; intra-wave address splits + cross-half shfl (ds_permute)
//   doubled step time. So R10 removes LDS from the dot entirely:
//   - each wave polls its own 64-element k-chunk straight into VGPRs
//     (the poll IS the load; no LDS staging round trip),
//   - dot: 64x { v_readlane h[k] -> SGPR; v_fmac with w[k] } — VALU only,
//   - per-wave independence -> single barrier/step (part[] double-buffered),
//   - tail + ONE coalesced 128B publish exactly as R7 (wave 0, lanes 0-15).
// Invariants (hard-won): no cache-wide fences (R2); no runtime indexing of
//   private arrays (R4); <=64 weight floats/lane (R5/R6/R8); publish = one
//   wave, one full line (R6); wave-uniform or register-only broadcast (R9).

#define T_SEQ 4096
#define HDIM  512
#define NWG_L 32
#define NTH   1024

typedef unsigned long long u64;

__device__ __forceinline__ u64 cohLoad(const u64* p) {
    return __hip_atomic_load(p, __ATOMIC_RELAXED, __HIP_MEMORY_SCOPE_AGENT);
}
__device__ __forceinline__ void cohStore(u64* p, u64 v) {
    __hip_atomic_store(p, v, __ATOMIC_RELAXED, __HIP_MEMORY_SCOPE_AGENT);
}
__device__ __forceinline__ float fsigmoid(float x) {
    return __builtin_amdgcn_rcpf(1.f + __expf(-x));
}
__device__ __forceinline__ float ftanh(float x) {
    float e = __expf(2.f * fabsf(x));           // +inf ok -> t = 1
    float t = 1.f - 2.f * __builtin_amdgcn_rcpf(e + 1.f);
    return copysignf(t, x);
}
__device__ __forceinline__ float bcast(float v, int k) {
    return __uint_as_float(__builtin_amdgcn_readlane(__float_as_uint(v), k));
}

// ---------------------------------------------------------------------------
// Tiled fp32 GEMM (final projection): C[M][N] = A[M][K] * B[N][K]^T + bias[n]
// ---------------------------------------------------------------------------
template <int BM, int BN, int BK>
__global__ __launch_bounds__(256)
void gemm_abt(const float* __restrict__ A, const float* __restrict__ B,
              const float* __restrict__ bias1,
              float* __restrict__ C, int M, int N, int K) {
    constexpr int NTX = BN / 4;
    constexpr int NTY = 256 / NTX;
    constexpr int TM  = BM / NTY;
    __shared__ float As[BM][BK + 1];
    __shared__ float Bs[BN][BK + 1];

    const int tid = threadIdx.x;
    const int tx = tid % NTX;
    const int ty = tid / NTX;
    const int m0 = blockIdx.y * BM;
    const int n0 = blockIdx.x * BN;

    float acc[TM][4];
    #pragma unroll
    for (int i = 0; i < TM; ++i)
        #pragma unroll
        for (int j = 0; j < 4; ++j) acc[i][j] = 0.f;

    for (int k0 = 0; k0 < K; k0 += BK) {
        constexpr int AV = BM * BK / 4;
        #pragma unroll
        for (int i = tid; i < AV; i += 256) {
            int r = i / (BK / 4), c4 = i % (BK / 4);
            float4 v = *(const float4*)(A + (size_t)(m0 + r) * K + k0 + c4 * 4);
            As[r][c4 * 4 + 0] = v.x; As[r][c4 * 4 + 1] = v.y;
            As[r][c4 * 4 + 2] = v.z; As[r][c4 * 4 + 3] = v.w;
        }
        constexpr int BV = BN * BK / 4;
        #pragma unroll
        for (int i = tid; i < BV; i += 256) {
            int r = i / (BK / 4), c4 = i % (BK / 4);
            float4 v = *(const float4*)(B + (size_t)(n0 + r) * K + k0 + c4 * 4);
            Bs[r][c4 * 4 + 0] = v.x; Bs[r][c4 * 4 + 1] = v.y;
            Bs[r][c4 * 4 + 2] = v.z; Bs[r][c4 * 4 + 3] = v.w;
        }
        __syncthreads();
        #pragma unroll
        for (int kk = 0; kk < BK; ++kk) {
            float a[TM], b[4];
            #pragma unroll
            for (int i = 0; i < TM; ++i) a[i] = As[ty * TM + i][kk];
            #pragma unroll
            for (int j = 0; j < 4; ++j) b[j] = Bs[tx * 4 + j][kk];
            #pragma unroll
            for (int i = 0; i < TM; ++i)
                #pragma unroll
                for (int j = 0; j < 4; ++j) acc[i][j] += a[i] * b[j];
        }
        __syncthreads();
    }

    #pragma unroll
    for (int j = 0; j < 4; ++j) {
        float bv = bias1 ? bias1[n0 + tx * 4 + j] : 0.f;
        #pragma unroll
        for (int i = 0; i < TM; ++i) acc[i][j] += bv;
    }
    #pragma unroll
    for (int i = 0; i < TM; ++i) {
        int m = m0 + ty * TM + i;
        float4 v = make_float4(acc[i][0], acc[i][1], acc[i][2], acc[i][3]);
        *(float4*)(C + (size_t)m * N + n0 + tx * 4) = v;
    }
}

// ---------------------------------------------------------------------------
__global__ void unpack_h(const u64* __restrict__ hp, float* __restrict__ out,
                         int n) {
    int i = blockIdx.x * blockDim.x + threadIdx.x;
    if (i < n) out[i] = __uint_as_float((unsigned)hp[i]);
}

// ---------------------------------------------------------------------------
// 32 WGs/layer x 1024 thr (16 waves). Lane = row (gate*16 + col_local).
// Layers 1/2: wave wv owns k-chunk [wv*64,+64) of concat [prev-h; own-h]:
//   wv<8 -> prev-h / Wih, wv>=8 -> own-h / Whh. Lane polls one element into
//   a VGPR; dot = 64x readlane-broadcast + fmac against w[64].
// Layer 0: wave wv owns own-h k [wv*32,+32) (lanes 0-31 poll); wave 15 also
//   handles x (32 floats of seq, weights in w[32..63]).
// ---------------------------------------------------------------------------
__global__ __launch_bounds__(NTH, 4)
void lstm_fused(const float* __restrict__ seq,
                const float* __restrict__ Wih1, const float* __restrict__ Whh1,
                const float* __restrict__ bih1, const float* __restrict__ bhh1,
                const float* __restrict__ Wih2, const float* __restrict__ Whh2,
                const float* __restrict__ bih2, const float* __restrict__ bhh2,
                const float* __restrict__ Wih3, const float* __restrict__ Whh3,
                const float* __restrict__ bih3, const float* __restrict__ bhh3,
                u64* __restrict__ hp) {
    __shared__ float part[2][NTH];      // [pb][wv*64 + row]

    const int blk   = blockIdx.x;
    const int layer = blk >> 5;
    const int g     = blk & 31;
    const int tid   = threadIdx.x;
    const int wv    = tid >> 6;          // 0..15
    const int lane  = tid & 63;          // = row (gate*16 + col_local)
    const int grow  = (lane >> 4) * HDIM + g * 16 + (lane & 15);

    const float* Wih = layer == 0 ? Wih1 : (layer == 1 ? Wih2 : Wih3);
    const float* Whh = layer == 0 ? Whh1 : (layer == 1 ? Whh2 : Whh3);
    const float* bih = layer == 0 ? bih1 : (layer == 1 ? bih2 : bih3);
    const float* bhh = layer == 0 ? bhh1 : (layer == 1 ? bhh2 : bhh3);

    // ---- 64 weight floats/lane (loop-constant indexing only) ----
    float w[64];
    #pragma unroll
    for (int m = 0; m < 64; ++m) w[m] = 0.f;
    if (layer == 0) {
        const float* wp = Whh + (size_t)grow * HDIM + wv * 32;
        #pragma unroll
        for (int i = 0; i < 8; ++i) {
            float4 v = ((const float4*)wp)[i];
            w[4*i+0]=v.x; w[4*i+1]=v.y; w[4*i+2]=v.z; w[4*i+3]=v.w;
        }
        if (wv == 15) {   // x weights -> w[32..63]
            const float* xp = Wih + (size_t)grow * 32;
            #pragma unroll
            for (int i = 0; i < 8; ++i) {
                float4 v = ((const float4*)xp)[i];
                w[32+4*i+0]=v.x; w[32+4*i+1]=v.y;
                w[32+4*i+2]=v.z; w[32+4*i+3]=v.w;
            }
        }
    } else {
        const float* wp = (wv < 8)
            ? Wih + (size_t)grow * HDIM + wv * 64
            : Whh + (size_t)grow * HDIM + (wv - 8) * 64;
        #pragma unroll
        for (int i = 0; i < 16; ++i) {
            float4 v = ((const float4*)wp)[i];
            w[4*i+0]=v.x; w[4*i+1]=v.y; w[4*i+2]=v.z; w[4*i+3]=v.w;
        }
    }
    #pragma unroll
    for (int m = 0; m < 64; ++m) asm volatile("" : "+v"(w[m]));

    const float brow = bih[grow] + bhh[grow];

    u64*       hpOwn  = hp + (size_t)layer * T_SEQ * HDIM;
    const u64* hpPrev = hp + (size_t)(layer > 0 ? layer - 1 : 0) * T_SEQ * HDIM;

    float c = 0.f;   // cell state (wave 0, lanes 0..15)

    for (unsigned t = 0; t < T_SEQ; ++t) {
        const int pb = t & 1;

        // ---- per-wave poll: chunk element straight into a VGPR ----
        float hval = 0.f;
        float xval = 0.f;
        if (layer == 0) {
            if (lane < 32 && t > 0) {
                const u64* ph = hpOwn + (size_t)(t - 1) * HDIM + wv * 32 + lane;
                u64 v;
                do { v = cohLoad(ph); } while ((unsigned)(v >> 32) != t);
                hval = __uint_as_float((unsigned)v);
            }
            if (wv == 15 && lane < 32)
                xval = seq[(size_t)t * 32 + lane];
        } else {
            if (wv < 8) {                        // prev-layer h[t], tag t+1
                const u64* px = hpPrev + (size_t)t * HDIM + wv * 64 + lane;
                u64 v;
                do { v = cohLoad(px); } while ((unsigned)(v >> 32) != t + 1u);
                hval = __uint_as_float((unsigned)v);
            } else if (t > 0) {                  // own h[t-1], tag t
                const u64* ph = hpOwn + (size_t)(t - 1) * HDIM
                              + (wv - 8) * 64 + lane;
                u64 v;
                do { v = cohLoad(ph); } while ((unsigned)(v >> 32) != t);
                hval = __uint_as_float((unsigned)v);
            }
        }

        // ---- dot: readlane broadcast + fmac, NO LDS ----
        float pe = 0.f, po = 0.f;
        if (layer == 0) {
            #pragma unroll
            for (int k = 0; k < 32; k += 2) {
                pe = fmaf(bcast(hval, k),     w[k],     pe);
                po = fmaf(bcast(hval, k + 1), w[k + 1], po);
            }
            if (wv == 15) {
                #pragma unroll
                for (int k = 0; k < 32; k += 2) {
                    pe = fmaf(bcast(xval, k),     w[32 + k],     pe);
                    po = fmaf(bcast(xval, k + 1), w[32 + k + 1], po);
                }
            }
        } else {
            #pragma unroll
            for (int k = 0; k < 64; k += 2) {
                pe = fmaf(bcast(hval, k),     w[k],     pe);
                po = fmaf(bcast(hval, k + 1), w[k + 1], po);
            }
        }
        part[pb][wv * 64 + lane] = pe + po;
        __syncthreads();

        // ---- wave 0: cross-wave sum, gates, ONE coalesced 128B publish ----
        if (wv == 0) {
            float tot = brow;
            #pragma unroll
            for (int wvv = 0; wvv < 16; ++wvv) tot += part[pb][wvv * 64 + lane];
            const int c16 = lane & 15;
            float ai = __shfl(tot, c16 +  0, 64);
            float af = __shfl(tot, c16 + 16, 64);
            float ag = __shfl(tot, c16 + 32, 64);
            float ao = __shfl(tot, c16 + 48, 64);
            if (lane < 16) {
                float iv = fsigmoid(ai);
                float fv = fsigmoid(af);
                float gv = ftanh(ag);
                float ov = fsigmoid(ao);
                c = fv * c + iv * gv;
                float h = ov * ftanh(c);
                u64 pkt = (u64)__float_as_uint(h) | ((u64)(t + 1u) << 32);
                cohStore(hpOwn + (size_t)t * HDIM + g * 16 + lane, pkt);
            }
        }
        // Other waves roll straight into polling t+1 (no pre-dot barrier:
        // each wave consumes only its own polled registers). part[] is
        // double-buffered; writes to part[pb] recur only at t+2, after
        // barrier(t+1), which wave 0 reaches only after its tail(t) reads.
    }
}

// ---------------------------------------------------------------------------
extern "C" void kernel_launch(void* const* d_in, const int* in_sizes, int n_in,
                              void* d_out, int out_size, void* d_ws, size_t ws_size,
                              hipStream_t stream) {
    const float* seq   = (const float*)d_in[0];
    const float* W_ih1 = (const float*)d_in[1];
    const float* W_hh1 = (const float*)d_in[2];
    const float* b_ih1 = (const float*)d_in[3];
    const float* b_hh1 = (const float*)d_in[4];
    const float* W_ih2 = (const float*)d_in[5];
    const float* W_hh2 = (const float*)d_in[6];
    const float* b_ih2 = (const float*)d_in[7];
    const float* b_hh2 = (const float*)d_in[8];
    const float* W_ih3 = (const float*)d_in[9];
    const float* W_hh3 = (const float*)d_in[10];
    const float* b_ih3 = (const float*)d_in[11];
    const float* b_hh3 = (const float*)d_in[12];
    const float* W_out = (const float*)d_in[13];
    const float* b_out = (const float*)d_in[14];
    float* out = (float*)d_out;

    // Workspace: hp[3][T][512] packed u64 (50.3MB); hs2 floats reuse the
    // dead layer-0 packed region after the recurrence.
    u64*   hp   = (u64*)d_ws;
    float* hs2f = (float*)d_ws;
    const u64* hp2 = hp + (size_t)2 * T_SEQ * HDIM;

    hipMemsetAsync(hp, 0, (size_t)3 * T_SEQ * HDIM * sizeof(u64), stream);

    lstm_fused<<<3 * NWG_L, NTH, 0, stream>>>(
        seq, W_ih1, W_hh1, b_ih1, b_hh1, W_ih2, W_hh2, b_ih2, b_hh2,
        W_ih3, W_hh3, b_ih3, b_hh3, hp);

    const int n = T_SEQ * HDIM;
    unpack_h<<<(n + 255) / 256, 256, 0, stream>>>(hp2, hs2f, n);

    gemm_abt<64, 32, 32><<<dim3(1, T_SEQ / 64), 256, 0, stream>>>(
        hs2f, W_out, b_out, out, T_SEQ, 32, HDIM);
}